// Round 1
// 619.551 us; speedup vs baseline: 1.0500x; 1.0500x over previous
//
#include <hip/hip_runtime.h>

// Circular depthwise 7x7 conv, NHWC, fp32.
// out[b,h,w,c] = sum_{i,j} K[c,i,j] * x[b,(h+3-i)%H,(w+3-j)%W,c]

#define Bn 8
#define Hn 224
#define Wn 224
#define Cn 192
#define Kn 7
#define TW 16          // output columns per thread (64 acc VGPRs)
#define TH 4           // output rows per block
#define C4 (Cn/4)      // 48 float4 channel groups

// Transpose (C,7,7) weights -> wT[(i*7+j)*C + c] so channel dim is contiguous.
__global__ void transpose_weights(const float* __restrict__ k, float* __restrict__ wT) {
    int o = blockIdx.x * 256 + threadIdx.x;
    if (o < Cn * Kn * Kn) {
        int c = o % Cn;
        int r = o / Cn;              // r = i*7 + j
        wT[o] = k[c * (Kn * Kn) + r];
    }
}

__global__ __launch_bounds__(192, 2)
void dwconv7x7(const float4* __restrict__ x, const float4* __restrict__ wT,
               float4* __restrict__ out) {
    const int tx = threadIdx.x;               // 0..47 channel group
    const int ty = threadIdx.y;               // 0..3 row within tile

    // --- XCD-aware swizzle -------------------------------------------------
    // 6272 blocks = 8 XCDs x 784, and 784 = 14 x 56 = one full batch image.
    // Round-robin dispatch => XCD = lin % 8. Give each XCD one batch, and
    // enumerate y-fastest within the XCD so vertical halo partners (which
    // share 6 rows x 22 cols) are temporally adjacent on the same L2.
    // Bijective: 6272 % 8 == 0.
    const int lin = blockIdx.x + 14 * (blockIdx.y + 56 * blockIdx.z);
    const int b   = lin & 7;                  // batch == XCD
    const int q   = lin >> 3;                 // 0..783 within XCD
    const int yt  = q % 56;                   // h tile (fastest)
    const int xt  = q / 56;                   // w tile

    const int w0 = xt * TW;
    const int h  = yt * TH + ty;

    float4 acc[TW];
#pragma unroll
    for (int t = 0; t < TW; ++t) acc[t] = make_float4(0.f, 0.f, 0.f, 0.f);

    for (int i = 0; i < Kn; ++i) {
        int row = h + 3 - i;
        row += (row < 0)   ? Hn : 0;
        row -= (row >= Hn) ? Hn : 0;
        const float4* __restrict__ xrow = x + (size_t)(b * Hn + row) * (Wn * C4) + tx;

        float4 wv[Kn];
#pragma unroll
        for (int j = 0; j < Kn; ++j) wv[j] = wT[(i * Kn + j) * C4 + tx];

#pragma unroll
        for (int u = 0; u < TW + 6; ++u) {
            int col = w0 + u - 3;
            col += (col < 0)   ? Wn : 0;
            col -= (col >= Wn) ? Wn : 0;
            float4 xv = xrow[col * C4];
#pragma unroll
            for (int j = 0; j < Kn; ++j) {
                int tw = u + j - 6;              // compile-time after unroll
                if (tw >= 0 && tw < TW) {
                    acc[tw].x += wv[j].x * xv.x;
                    acc[tw].y += wv[j].y * xv.y;
                    acc[tw].z += wv[j].z * xv.z;
                    acc[tw].w += wv[j].w * xv.w;
                }
            }
        }
    }

    float4* __restrict__ orow = out + (size_t)(b * Hn + h) * (Wn * C4) + tx;
#pragma unroll
    for (int t = 0; t < TW; ++t) orow[(w0 + t) * C4] = acc[t];
}

extern "C" void kernel_launch(void* const* d_in, const int* in_sizes, int n_in,
                              void* d_out, int out_size, void* d_ws, size_t ws_size,
                              hipStream_t stream) {
    const float* x = (const float*)d_in[0];          // (8,224,224,192) fp32
    const float* k = (const float*)d_in[1];          // (192,7,7) fp32
    float* wT = (float*)d_ws;                        // 9408 floats scratch

    int nW = Cn * Kn * Kn;
    transpose_weights<<<(nW + 255) / 256, 256, 0, stream>>>(k, wT);

    dim3 grid(Wn / TW, Hn / TH, Bn);                 // (14, 56, 8)
    dim3 block(C4, TH, 1);                           // (48, 4) = 192 threads
    dwconv7x7<<<grid, block, 0, stream>>>((const float4*)x, (const float4*)wT,
                                          (float4*)d_out);
}

// Round 2
// 617.787 us; speedup vs baseline: 1.0530x; 1.0029x over previous
//
#include <hip/hip_runtime.h>

// Circular depthwise 7x7 conv, NHWC, fp32.
// out[b,h,w,c] = sum_{i,j} K[c,i,j] * x[b,(h+3-i)%H,(w+3-j)%W,c]

#define Bn 8
#define Hn 224
#define Wn 224
#define Cn 192
#define Kn 7
#define TW 16          // output columns per thread (64 acc VGPRs)
#define TH 4           // output rows per block
#define C4 (Cn/4)      // 48 float4 channel groups

// Transpose (C,7,7) weights -> wT[(i*7+j)*C + c] so channel dim is contiguous.
__global__ void transpose_weights(const float* __restrict__ k, float* __restrict__ wT) {
    int o = blockIdx.x * 256 + threadIdx.x;
    if (o < Cn * Kn * Kn) {
        int c = o % Cn;
        int r = o / Cn;              // r = i*7 + j
        wT[o] = k[c * (Kn * Kn) + r];
    }
}

// FMA one input column (index U in the 22-wide halo row) into all valid acc taps.
#define FMA_U(U, XV) {                                                  \
    const float4 xv_ = (XV);                                            \
    _Pragma("unroll")                                                   \
    for (int j = 0; j < Kn; ++j) {                                      \
        int tw = (U) + j - 6;            /* compile-time after unroll */\
        if (tw >= 0 && tw < TW) {                                       \
            acc[tw].x += wv[j].x * xv_.x;                               \
            acc[tw].y += wv[j].y * xv_.y;                               \
            acc[tw].z += wv[j].z * xv_.z;                               \
            acc[tw].w += wv[j].w * xv_.w;                               \
        }                                                               \
    }                                                                   \
}

__global__ __launch_bounds__(192, 2)
void dwconv7x7(const float4* __restrict__ x, const float4* __restrict__ wT,
               float4* __restrict__ out) {
    const int tx = threadIdx.x;               // 0..47 channel group
    const int ty = threadIdx.y;               // 0..3 row within tile

    // --- XCD-aware swizzle (kept from R1: batch == XCD, y-fastest) ---------
    const int lin = blockIdx.x + 14 * (blockIdx.y + 56 * blockIdx.z);
    const int b   = lin & 7;                  // batch == XCD
    const int q   = lin >> 3;                 // 0..783 within XCD
    const int yt  = q % 56;                   // h tile (fastest)
    const int xt  = q / 56;                   // w tile

    const int w0 = xt * TW;
    const int h  = yt * TH + ty;

    // Hoisted column offsets (float4 units) — computed once, reused for all 7 rows.
    int coff[TW + 6];
#pragma unroll
    for (int u = 0; u < TW + 6; ++u) {
        int col = w0 + u - 3;
        col += (col < 0)   ? Wn : 0;
        col -= (col >= Wn) ? Wn : 0;
        coff[u] = col * C4;
    }

    float4 acc[TW];
#pragma unroll
    for (int t = 0; t < TW; ++t) acc[t] = make_float4(0.f, 0.f, 0.f, 0.f);

    const float4* __restrict__ xb = x + (size_t)b * ((size_t)Hn * Wn * C4) + tx;

#pragma unroll 1
    for (int i = 0; i < Kn; ++i) {
        int row = h + 3 - i;
        row += (row < 0)   ? Hn : 0;
        row -= (row >= Hn) ? Hn : 0;
        const float4* __restrict__ xrow = xb + (size_t)row * (Wn * C4);

        float4 wv[Kn];
#pragma unroll
        for (int j = 0; j < Kn; ++j) wv[j] = wT[(i * Kn + j) * C4 + tx];

        // Software-pipelined row processing: chunks of 8 columns, two buffers.
        float4 bufA[8], bufB[8];
#pragma unroll
        for (int u = 0; u < 8; ++u) bufA[u] = xrow[coff[u]];        // issue 0..7
#pragma unroll
        for (int u = 0; u < 8; ++u) bufB[u] = xrow[coff[8 + u]];    // issue 8..15

        // FMA chunk 0 (waits only for bufA; bufB still in flight)
#pragma unroll
        for (int u = 0; u < 8; ++u) FMA_U(u, bufA[u]);

        // issue 16..21 into bufA while chunk-1 FMAs run
#pragma unroll
        for (int u = 0; u < 6; ++u) bufA[u] = xrow[coff[16 + u]];

#pragma unroll
        for (int u = 0; u < 8; ++u) FMA_U(8 + u, bufB[u]);

#pragma unroll
        for (int u = 0; u < 6; ++u) FMA_U(16 + u, bufA[u]);
    }

    float4* __restrict__ orow = out + (size_t)(b * Hn + h) * (Wn * C4) + tx;
#pragma unroll
    for (int t = 0; t < TW; ++t) orow[(w0 + t) * C4] = acc[t];
}

extern "C" void kernel_launch(void* const* d_in, const int* in_sizes, int n_in,
                              void* d_out, int out_size, void* d_ws, size_t ws_size,
                              hipStream_t stream) {
    const float* x = (const float*)d_in[0];          // (8,224,224,192) fp32
    const float* k = (const float*)d_in[1];          // (192,7,7) fp32
    float* wT = (float*)d_ws;                        // 9408 floats scratch

    int nW = Cn * Kn * Kn;
    transpose_weights<<<(nW + 255) / 256, 256, 0, stream>>>(k, wT);

    dim3 grid(Wn / TW, Hn / TH, Bn);                 // (14, 56, 8)
    dim3 block(C4, TH, 1);                           // (48, 4) = 192 threads
    dwconv7x7<<<grid, block, 0, stream>>>((const float4*)x, (const float4*)wT,
                                          (float4*)d_out);
}

// Round 3
// 605.931 us; speedup vs baseline: 1.0736x; 1.0196x over previous
//
#include <hip/hip_runtime.h>

// Circular depthwise 7x7 conv, NHWC, fp32.
// out[b,h,w,c] = sum_{i,j} K[c,i,j] * x[b,(h+3-i)%H,(w+3-j)%W,c]

#define Bn 8
#define Hn 224
#define Wn 224
#define Cn 192
#define Kn 7
#define TW 8           // output columns per thread (32 acc VGPRs)
#define TH 4           // output rows per block
#define C4 (Cn/4)      // 48 float4 channel groups
#define NW4 (Cn*Kn*Kn/4)   // 2352 float4 weights

// Transpose (C,7,7) weights -> wT[(i*7+j)*C + c] so channel dim is contiguous.
__global__ void transpose_weights(const float* __restrict__ k, float* __restrict__ wT) {
    int o = blockIdx.x * 256 + threadIdx.x;
    if (o < Cn * Kn * Kn) {
        int c = o % Cn;
        int r = o / Cn;              // r = i*7 + j
        wT[o] = k[c * (Kn * Kn) + r];
    }
}

__global__ __launch_bounds__(192, 4)
void dwconv7x7(const float4* __restrict__ x, const float4* __restrict__ wT,
               float4* __restrict__ out) {
    // All 49*48 float4 weights staged in LDS once per block (37632 B).
    __shared__ float4 wlds[NW4];

    const int tx = threadIdx.x;               // 0..47 channel group
    const int ty = threadIdx.y;               // 0..3 row within tile
    const int tid = ty * C4 + tx;

    for (int o = tid; o < NW4; o += 192) wlds[o] = wT[o];
    __syncthreads();

    // --- XCD-aware swizzle: batch == XCD, y-fastest (12544 % 8 == 0) -------
    const int lin = blockIdx.x + 28 * (blockIdx.y + 56 * blockIdx.z);
    const int b   = lin & 7;                  // batch == XCD
    const int q   = lin >> 3;                 // 0..1567 within XCD (one image)
    const int yt  = q % 56;                   // h tile (fastest)
    const int xt  = q / 56;                   // w tile 0..27

    const int w0 = xt * TW;
    const int h  = yt * TH + ty;

    // Hoisted column offsets (float4 units), reused for all 7 rows.
    int coff[TW + 6];
#pragma unroll
    for (int u = 0; u < TW + 6; ++u) {
        int col = w0 + u - 3;
        col += (col < 0)   ? Wn : 0;
        col -= (col >= Wn) ? Wn : 0;
        coff[u] = col * C4;
    }

    float4 acc[TW];
#pragma unroll
    for (int t = 0; t < TW; ++t) acc[t] = make_float4(0.f, 0.f, 0.f, 0.f);

    const float4* __restrict__ xb = x + (size_t)b * ((size_t)Hn * Wn * C4) + tx;

#pragma unroll 1
    for (int i = 0; i < Kn; ++i) {
        int row = h + 3 - i;
        row += (row < 0)   ? Hn : 0;
        row -= (row >= Hn) ? Hn : 0;
        const float4* __restrict__ xrow = xb + (size_t)row * (Wn * C4);

        // Issue the entire halo row: 14 independent loads in flight.
        float4 xv[TW + 6];
#pragma unroll
        for (int u = 0; u < TW + 6; ++u) xv[u] = xrow[coff[u]];

        // j-major: one weight live at a time; j=6 first so the first FMAs
        // depend only on the earliest-issued loads (xv[0..7]).
#pragma unroll
        for (int j = Kn - 1; j >= 0; --j) {
            const float4 wvj = wlds[(i * Kn + j) * C4 + tx];
#pragma unroll
            for (int tw = 0; tw < TW; ++tw) {
                const float4 xvv = xv[tw + 6 - j];
                acc[tw].x += wvj.x * xvv.x;
                acc[tw].y += wvj.y * xvv.y;
                acc[tw].z += wvj.z * xvv.z;
                acc[tw].w += wvj.w * xvv.w;
            }
        }
    }

    float4* __restrict__ orow = out + (size_t)(b * Hn + h) * (Wn * C4) + tx;
#pragma unroll
    for (int t = 0; t < TW; ++t) orow[(w0 + t) * C4] = acc[t];
}

extern "C" void kernel_launch(void* const* d_in, const int* in_sizes, int n_in,
                              void* d_out, int out_size, void* d_ws, size_t ws_size,
                              hipStream_t stream) {
    const float* x = (const float*)d_in[0];          // (8,224,224,192) fp32
    const float* k = (const float*)d_in[1];          // (192,7,7) fp32
    float* wT = (float*)d_ws;                        // 9408 floats scratch

    int nW = Cn * Kn * Kn;
    transpose_weights<<<(nW + 255) / 256, 256, 0, stream>>>(k, wT);

    dim3 grid(Wn / TW, Hn / TH, Bn);                 // (28, 56, 8)
    dim3 block(C4, TH, 1);                           // (48, 4) = 192 threads
    dwconv7x7<<<grid, block, 0, stream>>>((const float4*)x, (const float4*)wT,
                                          (float4*)d_out);
}